// Round 1
// baseline (259.176 us; speedup 1.0000x reference)
//
#include <hip/hip_runtime.h>

// Problem constants (fixed by the reference)
#define BN 16
#define HN 128
#define WN 128
#define CN 64
#define HO (HN / 2)              // 64
#define WO (WN / 2)              // 64
#define C4 (CN / 4)              // 16 float4s per channel slice
#define OUT_PER (BN * HO * WO * CN)   // 4,194,304 elements per output tensor
#define ROW4 (WN * C4)           // one input row in float4 units = 2048

// Quaternion norm, matching the reference bit-exactly:
//   sqrt(((x0^2 + x1^2) + x2^2) + x3^2), no FMA contraction.
__device__ __forceinline__ float4 qnorm4(const float4 a, const float4 b,
                                         const float4 c, const float4 d) {
#pragma clang fp contract(off)
    float4 r;
    r.x = sqrtf(((a.x * a.x + b.x * b.x) + c.x * c.x) + d.x * d.x);
    r.y = sqrtf(((a.y * a.y + b.y * b.y) + c.y * c.y) + d.y * d.y);
    r.z = sqrtf(((a.z * a.z + b.z * b.z) + c.z * c.z) + d.z * d.z);
    r.w = sqrtf(((a.w * a.w + b.w * b.w) + c.w * c.w) + d.w * d.w);
    return r;
}

// Per-element strict-> update: first-max tie-break (matches TF/np argmax).
#define UPD_ELEM(f)                                                            \
    do {                                                                       \
        bool m = n.f > bn.f;                                                   \
        bn.f = m ? n.f : bn.f;                                                 \
        v0.f = m ? a0.f : v0.f;                                                \
        v1.f = m ? a1.f : v1.f;                                                \
        v2.f = m ? a2.f : v2.f;                                                \
        v3.f = m ? a3.f : v3.f;                                                \
    } while (0)

__global__ __launch_bounds__(256) void maxnorm_pool_kernel(
    const float4* __restrict__ x0, const float4* __restrict__ x1,
    const float4* __restrict__ x2, const float4* __restrict__ x3,
    float4* __restrict__ out) {
    const int t = blockIdx.x * 256 + threadIdx.x;   // 0 .. 1,048,575
    const int c4  = t & (C4 - 1);                   // float4 index within C
    const int pix = t >> 4;                         // b*HO*WO + ho*WO + wo
    const int wo  = pix & (WO - 1);
    const int rst = pix >> 6;
    const int ho  = rst & (HO - 1);
    const int b   = rst >> 6;

    // float4-unit offset of window element (dh=0, dw=0)
    const int base = ((b * HN + 2 * ho) * WN + 2 * wo) * C4 + c4;
    const int o01 = base + C4;          // (0,1)
    const int o10 = base + ROW4;        // (1,0)
    const int o11 = base + ROW4 + C4;   // (1,1)

    // Load all 4 windows x 4 components up front (16 outstanding dwordx4).
    float4 w0a = x0[base], w0b = x1[base], w0c = x2[base], w0d = x3[base];
    float4 w1a = x0[o01],  w1b = x1[o01],  w1c = x2[o01],  w1d = x3[o01];
    float4 w2a = x0[o10],  w2b = x1[o10],  w2c = x2[o10],  w2d = x3[o10];
    float4 w3a = x0[o11],  w3b = x1[o11],  w3c = x2[o11],  w3d = x3[o11];

    // Window 0 initializes best state.
    float4 bn = qnorm4(w0a, w0b, w0c, w0d);
    float4 v0 = w0a, v1 = w0b, v2 = w0c, v3 = w0d;

    // Windows 1..3 (row-major h-then-w order, matching reference flattening).
    {
        float4 a0 = w1a, a1 = w1b, a2 = w1c, a3 = w1d;
        float4 n = qnorm4(a0, a1, a2, a3);
        UPD_ELEM(x); UPD_ELEM(y); UPD_ELEM(z); UPD_ELEM(w);
    }
    {
        float4 a0 = w2a, a1 = w2b, a2 = w2c, a3 = w2d;
        float4 n = qnorm4(a0, a1, a2, a3);
        UPD_ELEM(x); UPD_ELEM(y); UPD_ELEM(z); UPD_ELEM(w);
    }
    {
        float4 a0 = w3a, a1 = w3b, a2 = w3c, a3 = w3d;
        float4 n = qnorm4(a0, a1, a2, a3);
        UPD_ELEM(x); UPD_ELEM(y); UPD_ELEM(z); UPD_ELEM(w);
    }

    // Outputs concatenated flat in return order; each is fully coalesced.
    const int oi = pix * C4 + c4;
    out[oi]                  = v0;
    out[OUT_PER / 4 + oi]    = v1;
    out[2 * (OUT_PER / 4) + oi] = v2;
    out[3 * (OUT_PER / 4) + oi] = v3;
}

extern "C" void kernel_launch(void* const* d_in, const int* in_sizes, int n_in,
                              void* d_out, int out_size, void* d_ws, size_t ws_size,
                              hipStream_t stream) {
    const float4* x0 = (const float4*)d_in[0];
    const float4* x1 = (const float4*)d_in[1];
    const float4* x2 = (const float4*)d_in[2];
    const float4* x3 = (const float4*)d_in[3];
    float4* out = (float4*)d_out;

    const int total_threads = BN * HO * WO * C4;   // 1,048,576
    const int block = 256;
    const int grid = total_threads / block;        // 4096
    maxnorm_pool_kernel<<<grid, block, 0, stream>>>(x0, x1, x2, x3, out);
}

// Round 2
// 255.938 us; speedup vs baseline: 1.0127x; 1.0127x over previous
//
#include <hip/hip_runtime.h>

// Problem constants (fixed by the reference)
#define BN 16
#define HN 128
#define WN 128
#define CN 64
#define HO 64
#define WO 64
#define C4 16                         // float4s per channel slice
#define ROW4 (WN * C4)                // 2048 float4 per input row
#define OUTQ (BN * HO * WO * C4)      // 1,048,576 float4 per output tensor

// Quaternion norm, matching the reference bit-exactly:
//   sqrt(((x0^2 + x1^2) + x2^2) + x3^2), no FMA contraction.
__device__ __forceinline__ float4 qnorm4(const float4 a, const float4 b,
                                         const float4 c, const float4 d) {
#pragma clang fp contract(off)
    float4 r;
    r.x = sqrtf(((a.x * a.x + b.x * b.x) + c.x * c.x) + d.x * d.x);
    r.y = sqrtf(((a.y * a.y + b.y * b.y) + c.y * c.y) + d.y * d.y);
    r.z = sqrtf(((a.z * a.z + b.z * b.z) + c.z * c.z) + d.z * d.z);
    r.w = sqrtf(((a.w * a.w + b.w * b.w) + c.w * c.w) + d.w * d.w);
    return r;
}

__device__ __forceinline__ float4 shfl16(float4 v) {
    float4 r;
    r.x = __shfl_xor(v.x, 16);
    r.y = __shfl_xor(v.y, 16);
    r.z = __shfl_xor(v.z, 16);
    r.w = __shfl_xor(v.w, 16);
    return r;
}

// Vertical (dh) reduce, strict > keeps the earlier (dh=0) window element.
#define VERT(f, k)                                                             \
    do {                                                                       \
        bool m = n1.f > n0.f;                                                  \
        bn.f = m ? n1.f : n0.f;                                                \
        s0.f = m ? a0r1.f : a0r0.f;                                            \
        s1.f = m ? a1r1.f : a1r0.f;                                            \
        s2.f = m ? a2r1.f : a2r0.f;                                            \
        s3.f = m ? a3r1.f : a3r0.f;                                            \
        rows |= (m ? (1 << (k)) : 0);                                          \
    } while (0)

// Horizontal (dw) combine with exact first-max tie-break over the
// (dh,dw) flatten order [(0,0),(0,1),(1,0),(1,1)]:
//   even-column winner index = 2*rE, odd-column = 2*rO+1.
//   take odd iff nO > nE, or nO == nE and (rE==1 && rO==0).
#define HORZ(f, k)                                                             \
    do {                                                                       \
        bool rE = (rows >> (k)) & 1;                                           \
        bool rO = (rowsO >> (k)) & 1;                                          \
        bool tO = (bnO.f > bn.f) || ((bnO.f == bn.f) && rE && !rO);            \
        s0.f = tO ? p0.f : s0.f;                                               \
        s1.f = tO ? p1.f : s1.f;                                               \
        s2.f = tO ? p2.f : s2.f;                                               \
        s3.f = tO ? p3.f : s3.f;                                               \
    } while (0)

__global__ __launch_bounds__(256) void maxnorm_pool_kernel(
    const float4* __restrict__ x0, const float4* __restrict__ x1,
    const float4* __restrict__ x2, const float4* __restrict__ x3,
    float4* __restrict__ out) {
    // One thread per (input column of a row-pair, c4): 2,097,152 threads.
    // Lane l covers global float4 index waveBase + l -> every global load
    // is a contiguous 1 KB wave transaction.
    const int t = blockIdx.x * 256 + threadIdx.x;
    const int within = t & (ROW4 - 1);        // float4 index within the row
    const int rowIdx = t >> 11;               // b*HO + ho
    const int ho = rowIdx & (HO - 1);
    const int b  = rowIdx >> 6;

    const int g0 = (b * HN + 2 * ho) * ROW4 + within;  // row h = 2*ho
    const int g1 = g0 + ROW4;                          // row h = 2*ho + 1

    // 8 loads, all wave-contiguous.
    float4 a0r0 = x0[g0], a1r0 = x1[g0], a2r0 = x2[g0], a3r0 = x3[g0];
    float4 a0r1 = x0[g1], a1r1 = x1[g1], a2r1 = x2[g1], a3r1 = x3[g1];

    float4 n0 = qnorm4(a0r0, a1r0, a2r0, a3r0);
    float4 n1 = qnorm4(a0r1, a1r1, a2r1, a3r1);

    // Vertical reduce (per channel element).
    float4 bn, s0, s1, s2, s3;
    int rows = 0;
    VERT(x, 0); VERT(y, 1); VERT(z, 2); VERT(w, 3);

    // Exchange with the horizontal-neighbor lane (w and w^1 share lane^16).
    float4 bnO = shfl16(bn);
    float4 p0 = shfl16(s0), p1 = shfl16(s1), p2 = shfl16(s2), p3 = shfl16(s3);
    int rowsO = __shfl_xor(rows, 16);

    HORZ(x, 0); HORZ(y, 1); HORZ(z, 2); HORZ(w, 3);

    // Even-w lanes (dw == 0) hold the window result; store.
    if (((threadIdx.x >> 4) & 1) == 0) {
        const int c4 = within & (C4 - 1);
        const int wo = within >> 5;           // (within>>4) is w; >>1 -> wo
        const int oi = ((b * HO + ho) * WO + wo) * C4 + c4;
        out[oi]            = s0;
        out[OUTQ + oi]     = s1;
        out[2 * OUTQ + oi] = s2;
        out[3 * OUTQ + oi] = s3;
    }
}

extern "C" void kernel_launch(void* const* d_in, const int* in_sizes, int n_in,
                              void* d_out, int out_size, void* d_ws, size_t ws_size,
                              hipStream_t stream) {
    const float4* x0 = (const float4*)d_in[0];
    const float4* x1 = (const float4*)d_in[1];
    const float4* x2 = (const float4*)d_in[2];
    const float4* x3 = (const float4*)d_in[3];
    float4* out = (float4*)d_out;

    const int total_threads = BN * HO * ROW4;  // 2,097,152
    const int block = 256;
    const int grid = total_threads / block;    // 8192
    maxnorm_pool_kernel<<<grid, block, 0, stream>>>(x0, x1, x2, x3, out);
}

// Round 4
// 239.767 us; speedup vs baseline: 1.0809x; 1.0674x over previous
//
#include <hip/hip_runtime.h>

// Problem constants (fixed by the reference)
#define BN 16
#define HN 128
#define WN 128
#define CN 64
#define HO 64
#define WO 64
#define C4 16                         // float4s per channel slice
#define ROW4 (WN * C4)                // 2048 float4 per input row
#define OUTQ (BN * HO * WO * C4)      // 1,048,576 float4 per output tensor

// Native vector type accepted by __builtin_nontemporal_{load,store}
// (HIP's float4 is a struct; the builtin requires scalar/vector types).
typedef float f32x4 __attribute__((ext_vector_type(4)));

// Quaternion norm, matching the reference bit-exactly:
//   sqrt(((x0^2 + x1^2) + x2^2) + x3^2), no FMA contraction.
__device__ __forceinline__ f32x4 qnorm4(const f32x4 a, const f32x4 b,
                                        const f32x4 c, const f32x4 d) {
#pragma clang fp contract(off)
    f32x4 r;
    r.x = sqrtf(((a.x * a.x + b.x * b.x) + c.x * c.x) + d.x * d.x);
    r.y = sqrtf(((a.y * a.y + b.y * b.y) + c.y * c.y) + d.y * d.y);
    r.z = sqrtf(((a.z * a.z + b.z * b.z) + c.z * c.z) + d.z * d.z);
    r.w = sqrtf(((a.w * a.w + b.w * b.w) + c.w * c.w) + d.w * d.w);
    return r;
}

__device__ __forceinline__ f32x4 ntload(const f32x4* __restrict__ p) {
    // Non-temporal: evict-first / no-allocate hint. Still hits L2/L3 if
    // resident. Inputs are single-use -> don't let their miss-fills thrash
    // the Infinity Cache lines holding not-yet-read input.
    return __builtin_nontemporal_load(p);
}

__device__ __forceinline__ f32x4 shfl16(f32x4 v) {
    f32x4 r;
    r.x = __shfl_xor(v.x, 16);
    r.y = __shfl_xor(v.y, 16);
    r.z = __shfl_xor(v.z, 16);
    r.w = __shfl_xor(v.w, 16);
    return r;
}

// Vertical (dh) reduce, strict > keeps the earlier (dh=0) window element.
#define VERT(f, k)                                                             \
    do {                                                                       \
        bool m = n1.f > n0.f;                                                  \
        bn.f = m ? n1.f : n0.f;                                                \
        s0.f = m ? a0r1.f : a0r0.f;                                            \
        s1.f = m ? a1r1.f : a1r0.f;                                            \
        s2.f = m ? a2r1.f : a2r0.f;                                            \
        s3.f = m ? a3r1.f : a3r0.f;                                            \
        rows |= (m ? (1 << (k)) : 0);                                          \
    } while (0)

// Horizontal (dw) combine with exact first-max tie-break over the
// (dh,dw) flatten order [(0,0),(0,1),(1,0),(1,1)]:
//   even-column winner index = 2*rE, odd-column = 2*rO+1.
//   take odd iff nO > nE, or nO == nE and (rE==1 && rO==0).
#define HORZ(f, k)                                                             \
    do {                                                                       \
        bool rE = (rows >> (k)) & 1;                                           \
        bool rO = (rowsO >> (k)) & 1;                                          \
        bool tO = (bnO.f > bn.f) || ((bnO.f == bn.f) && rE && !rO);            \
        s0.f = tO ? p0.f : s0.f;                                               \
        s1.f = tO ? p1.f : s1.f;                                               \
        s2.f = tO ? p2.f : s2.f;                                               \
        s3.f = tO ? p3.f : s3.f;                                               \
    } while (0)

__global__ __launch_bounds__(256) void maxnorm_pool_kernel(
    const f32x4* __restrict__ x0, const f32x4* __restrict__ x1,
    const f32x4* __restrict__ x2, const f32x4* __restrict__ x3,
    f32x4* __restrict__ out) {
    // One thread per (input column of a row-pair, c4): 2,097,152 threads.
    // Lane l covers global float4 index waveBase + l -> every global load
    // is a contiguous 1 KB wave transaction.
    const int t = blockIdx.x * 256 + threadIdx.x;
    const int within = t & (ROW4 - 1);        // float4 index within the row
    const int rowIdx = t >> 11;               // b*HO + ho
    const int ho = rowIdx & (HO - 1);
    const int b  = rowIdx >> 6;

    const int g0 = (b * HN + 2 * ho) * ROW4 + within;  // row h = 2*ho
    const int g1 = g0 + ROW4;                          // row h = 2*ho + 1

    // 8 loads, all wave-contiguous, all non-temporal (single-use data).
    f32x4 a0r0 = ntload(x0 + g0), a1r0 = ntload(x1 + g0);
    f32x4 a2r0 = ntload(x2 + g0), a3r0 = ntload(x3 + g0);
    f32x4 a0r1 = ntload(x0 + g1), a1r1 = ntload(x1 + g1);
    f32x4 a2r1 = ntload(x2 + g1), a3r1 = ntload(x3 + g1);

    f32x4 n0 = qnorm4(a0r0, a1r0, a2r0, a3r0);
    f32x4 n1 = qnorm4(a0r1, a1r1, a2r1, a3r1);

    // Vertical reduce (per channel element).
    f32x4 bn, s0, s1, s2, s3;
    int rows = 0;
    VERT(x, 0); VERT(y, 1); VERT(z, 2); VERT(w, 3);

    // Exchange with the horizontal-neighbor lane (w and w^1 share lane^16).
    f32x4 bnO = shfl16(bn);
    f32x4 p0 = shfl16(s0), p1 = shfl16(s1), p2 = shfl16(s2), p3 = shfl16(s3);
    int rowsO = __shfl_xor(rows, 16);

    HORZ(x, 0); HORZ(y, 1); HORZ(z, 2); HORZ(w, 3);

    // Even-w lanes (dw == 0) hold the window result; store non-temporally
    // (output is never re-read in-kernel; keep it out of L3).
    if (((threadIdx.x >> 4) & 1) == 0) {
        const int c4 = within & (C4 - 1);
        const int wo = within >> 5;           // (within>>4) is w; >>1 -> wo
        const int oi = ((b * HO + ho) * WO + wo) * C4 + c4;
        __builtin_nontemporal_store(s0, out + oi);
        __builtin_nontemporal_store(s1, out + OUTQ + oi);
        __builtin_nontemporal_store(s2, out + 2 * OUTQ + oi);
        __builtin_nontemporal_store(s3, out + 3 * OUTQ + oi);
    }
}

extern "C" void kernel_launch(void* const* d_in, const int* in_sizes, int n_in,
                              void* d_out, int out_size, void* d_ws, size_t ws_size,
                              hipStream_t stream) {
    const f32x4* x0 = (const f32x4*)d_in[0];
    const f32x4* x1 = (const f32x4*)d_in[1];
    const f32x4* x2 = (const f32x4*)d_in[2];
    const f32x4* x3 = (const f32x4*)d_in[3];
    f32x4* out = (f32x4*)d_out;

    const int total_threads = BN * HO * ROW4;  // 2,097,152
    const int block = 256;
    const int grid = total_threads / block;    // 8192
    maxnorm_pool_kernel<<<grid, block, 0, stream>>>(x0, x1, x2, x3, out);
}